// Round 1
// baseline (545.756 us; speedup 1.0000x reference)
//
#include <hip/hip_runtime.h>
#include <hip/hip_bf16.h>
#include <stdint.h>

// Problem constants (QuantizedLinear NF4): x (4,2048,4096) f32, packed (4096,2048) i32,
// absmax (4096,) f32, bias (4096,) f32 -> out (4,2048,4096) f32.
#define M_DIM 8192
#define N_DIM 4096
#define K_DIM 4096

typedef __bf16 bf16_t;
typedef __attribute__((ext_vector_type(8))) __bf16 bf16x8;
typedef __attribute__((ext_vector_type(4))) float f32x4;

__constant__ float NF4_LUT[16] = {
    -1.0f, -0.6961928009986877f, -0.5250730514526367f, -0.39491748809814453f,
    -0.28444138169288635f, -0.18477343022823334f, -0.09105003625154495f, 0.0f,
    0.07958029955625534f, 0.16093020141124725f, 0.24611230194568634f,
    0.33791524171829224f, 0.44070982933044434f, 0.5626170039176941f,
    0.7229568362236023f, 1.0f};

// ---------------------------------------------------------------------------
// Kernel 1: NF4 dequant -> bf16 W, (N_DIM x K_DIM) row-major (k contiguous).
// Each thread: 4 packed int32 (16B load) -> 8 bf16 (16B store).
// ---------------------------------------------------------------------------
__global__ __launch_bounds__(256) void dequant_nf4_kernel(
    const int* __restrict__ packed, const float* __restrict__ absmax,
    bf16_t* __restrict__ W) {
  const int t = blockIdx.x * 256 + threadIdx.x;  // N_DIM*(K_DIM/2)/4 threads
  const int row = t >> 9;                        // (K_DIM/2)/4 = 512 chunks/row
  const int c = t & 511;
  const int4 p = ((const int4*)packed)[t];
  const float am = absmax[row];
  bf16x8 v;
  int bytes0 = p.x & 255, bytes1 = p.y & 255, bytes2 = p.z & 255, bytes3 = p.w & 255;
  v[0] = (bf16_t)(NF4_LUT[(bytes0 >> 4) & 15] * am);
  v[1] = (bf16_t)(NF4_LUT[bytes0 & 15] * am);
  v[2] = (bf16_t)(NF4_LUT[(bytes1 >> 4) & 15] * am);
  v[3] = (bf16_t)(NF4_LUT[bytes1 & 15] * am);
  v[4] = (bf16_t)(NF4_LUT[(bytes2 >> 4) & 15] * am);
  v[5] = (bf16_t)(NF4_LUT[bytes2 & 15] * am);
  v[6] = (bf16_t)(NF4_LUT[(bytes3 >> 4) & 15] * am);
  v[7] = (bf16_t)(NF4_LUT[bytes3 & 15] * am);
  *((bf16x8*)&W[(size_t)row * K_DIM + c * 8]) = v;
}

// ---------------------------------------------------------------------------
// Kernel 2: x f32 -> bf16 (RNE). Each thread: 32B load -> 16B store.
// ---------------------------------------------------------------------------
__global__ __launch_bounds__(256) void cvt_bf16_kernel(
    const float* __restrict__ x, bf16_t* __restrict__ y) {
  const int t = blockIdx.x * 256 + threadIdx.x;  // M_DIM*K_DIM/8 threads
  const float4 a = ((const float4*)x)[2 * t];
  const float4 b = ((const float4*)x)[2 * t + 1];
  bf16x8 v;
  v[0] = (bf16_t)a.x; v[1] = (bf16_t)a.y; v[2] = (bf16_t)a.z; v[3] = (bf16_t)a.w;
  v[4] = (bf16_t)b.x; v[5] = (bf16_t)b.y; v[6] = (bf16_t)b.z; v[7] = (bf16_t)b.w;
  *((bf16x8*)&y[(size_t)t * 8]) = v;
}

// ---------------------------------------------------------------------------
// Kernel 3: bf16 MFMA GEMM, m97 structure.
// A = x_bf16 (M x K), B = W (N x K, i.e. B^T layout), C = out (M x N) f32.
// 128x128 tile, BK=32, 256 threads = 2x2 waves, each wave 4x4 of 16x16x32.
// global_load_lds width=16 staging; LDS layout = exactly base + lane*16.
// ---------------------------------------------------------------------------
#define GLD_LDS16(g, l)                                                     \
  __builtin_amdgcn_global_load_lds(                                        \
      (const __attribute__((address_space(1))) void*)(g),                   \
      (__attribute__((address_space(3))) void*)(l), 16, 0, 0)

__global__ __launch_bounds__(256) void gemm_nf4_kernel(
    const bf16_t* __restrict__ A, const bf16_t* __restrict__ B,
    const float* __restrict__ bias, float* __restrict__ C) {
  constexpr int BM = 128, BN = 128, BK = 32;
  __shared__ __align__(16) bf16_t sA[BM * BK];  // [m][k] row-major, no pad
  __shared__ __align__(16) bf16_t sB[BN * BK];  // [n][k] row-major, no pad

  const int tid = threadIdx.x;
  const int wave = tid >> 6, lane = tid & 63;
  const int wr = wave >> 1, wc = wave & 1;     // 2x2 wave grid
  const int quad = lane >> 4, l15 = lane & 15;

  const int blockM = blockIdx.y * BM;
  const int blockN = blockIdx.x * BN;

  // Staging: thread covers row sr (0..63), k-chunk sk; second load rows 64..127.
  const int sr = tid >> 2;
  const int sk = (tid & 3) * 8;
  const bf16_t* gA0 = A + (size_t)(blockM + sr) * K_DIM + sk;
  const bf16_t* gA1 = gA0 + (size_t)64 * K_DIM;
  const bf16_t* gB0 = B + (size_t)(blockN + sr) * K_DIM + sk;
  const bf16_t* gB1 = gB0 + (size_t)64 * K_DIM;
  bf16_t* lA0 = &sA[tid * 8];
  bf16_t* lA1 = &sA[tid * 8 + 64 * BK];
  bf16_t* lB0 = &sB[tid * 8];
  bf16_t* lB1 = &sB[tid * 8 + 64 * BK];

  f32x4 acc[4][4];
#pragma unroll
  for (int i = 0; i < 4; ++i)
#pragma unroll
    for (int j = 0; j < 4; ++j) acc[i][j] = (f32x4)(0.0f);

  for (int k0 = 0; k0 < K_DIM; k0 += BK) {
    GLD_LDS16(gA0 + k0, lA0);
    GLD_LDS16(gA1 + k0, lA1);
    GLD_LDS16(gB0 + k0, lB0);
    GLD_LDS16(gB1 + k0, lB1);
    __syncthreads();  // drains vmcnt -> LDS tiles complete

    bf16x8 af[4], bfr[4];
#pragma unroll
    for (int i = 0; i < 4; ++i)
      af[i] = *(const bf16x8*)&sA[(wr * 64 + i * 16 + l15) * BK + quad * 8];
#pragma unroll
    for (int j = 0; j < 4; ++j)
      bfr[j] = *(const bf16x8*)&sB[(wc * 64 + j * 16 + l15) * BK + quad * 8];

#pragma unroll
    for (int i = 0; i < 4; ++i)
#pragma unroll
      for (int j = 0; j < 4; ++j)
        acc[i][j] = __builtin_amdgcn_mfma_f32_16x16x32_bf16(af[i], bfr[j],
                                                            acc[i][j], 0, 0, 0);
    __syncthreads();  // protect LDS from next iter's staging
  }

  // Epilogue: C/D layout col = lane&15 (n), row = quad*4 + reg (m). Fuse bias.
#pragma unroll
  for (int j = 0; j < 4; ++j) {
    const int n = blockN + wc * 64 + j * 16 + l15;
    const float bv = bias[n];
#pragma unroll
    for (int i = 0; i < 4; ++i) {
      const int m0 = blockM + wr * 64 + i * 16 + quad * 4;
      f32x4 v = acc[i][j];
      C[(size_t)(m0 + 0) * N_DIM + n] = v[0] + bv;
      C[(size_t)(m0 + 1) * N_DIM + n] = v[1] + bv;
      C[(size_t)(m0 + 2) * N_DIM + n] = v[2] + bv;
      C[(size_t)(m0 + 3) * N_DIM + n] = v[3] + bv;
    }
  }
}

// ---------------------------------------------------------------------------
// Fallback (only if ws_size is too small): naive on-the-fly dequant GEMM.
// ---------------------------------------------------------------------------
__global__ __launch_bounds__(256) void fallback_kernel(
    const float* __restrict__ x, const int* __restrict__ packed,
    const float* __restrict__ absmax, const float* __restrict__ bias,
    float* __restrict__ out) {
  const int idx = blockIdx.x * 256 + threadIdx.x;
  const int m = idx / N_DIM, n = idx % N_DIM;
  const int* prow = packed + (size_t)n * (K_DIM / 2);
  const float* xr = x + (size_t)m * K_DIM;
  float s = 0.0f;
  for (int p = 0; p < K_DIM / 2; ++p) {
    const int b = prow[p] & 255;
    s += xr[2 * p] * NF4_LUT[(b >> 4) & 15] + xr[2 * p + 1] * NF4_LUT[b & 15];
  }
  out[idx] = s * absmax[n] + bias[n];
}

extern "C" void kernel_launch(void* const* d_in, const int* in_sizes, int n_in,
                              void* d_out, int out_size, void* d_ws,
                              size_t ws_size, hipStream_t stream) {
  const float* x = (const float*)d_in[0];
  const int* packed = (const int*)d_in[1];
  const float* absmax = (const float*)d_in[2];
  const float* bias = (const float*)d_in[3];
  float* out = (float*)d_out;

  const size_t wBytes = (size_t)N_DIM * K_DIM * sizeof(bf16_t);  // 32 MB
  const size_t xBytes = (size_t)M_DIM * K_DIM * sizeof(bf16_t);  // 64 MB
  if (ws_size < wBytes + xBytes) {
    fallback_kernel<<<dim3((M_DIM * N_DIM) / 256), dim3(256), 0, stream>>>(
        x, packed, absmax, bias, out);
    return;
  }

  bf16_t* W = (bf16_t*)d_ws;
  bf16_t* xb = (bf16_t*)((char*)d_ws + wBytes);

  dequant_nf4_kernel<<<dim3((N_DIM * (K_DIM / 2) / 4) / 256), dim3(256), 0,
                       stream>>>(packed, absmax, W);
  cvt_bf16_kernel<<<dim3((M_DIM * K_DIM / 8) / 256), dim3(256), 0, stream>>>(
      x, xb);
  gemm_nf4_kernel<<<dim3(N_DIM / 128, M_DIM / 128), dim3(256), 0, stream>>>(
      xb, W, bias, out);
}